// Round 2
// baseline (389.241 us; speedup 1.0000x reference)
//
#include <hip/hip_runtime.h>
#include <hip/hip_bf16.h>
#include <math.h>

// Problem constants (B,C,H,W = 16,512,64,64; K=32)
#define BB 16
#define CC 512
#define NN 4096   // H*W
#define KK 32

// ws layout (floats):
// [0, 16384)                cwt  (C x K)  codewords transposed, c-major
// [16384, 16416)            c2   (K)      sum_c cw^2
// [16416, 16928)            asum (B*K)    sum_n A[b,n,k]
// [16928, 16928 + B*K*N)    A    (B,K,N)  softmax weights, k-major rows over n

// ---------------- K0: prep (transpose cw, c2, zero asum + out) ----------------
__global__ void prep_kernel(const float* __restrict__ cw, float* __restrict__ cwt,
                            float* __restrict__ c2, float* __restrict__ asum,
                            float* __restrict__ out) {
  int gid = blockIdx.x * blockDim.x + threadIdx.x;  // 16384 threads
  if (gid < BB * KK) asum[gid] = 0.0f;
  // zero out (B*K*C = 262144 floats = 65536 float4) for agg's atomicAdd
  float4 z = make_float4(0.f, 0.f, 0.f, 0.f);
  float4* o4 = (float4*)out;
#pragma unroll
  for (int j = 0; j < 4; ++j) o4[gid + j * 16384] = z;
  for (int idx = gid; idx < KK * CC; idx += 16384) {
    int c = idx >> 5, k = idx & 31;
    cwt[idx] = cw[k * CC + c];
  }
  __shared__ float c2p[KK][8];
  if (blockIdx.x == 0) {
    int k = threadIdx.x >> 3, j = threadIdx.x & 7;
    const float* row = cw + k * CC + j * 64;
    float s = 0.f;
    for (int i = 0; i < 64; ++i) s = fmaf(row[i], row[i], s);
    c2p[k][j] = s;
    __syncthreads();
    if (threadIdx.x < KK) {
      float t = 0.f;
      for (int j2 = 0; j2 < 8; ++j2) t += c2p[threadIdx.x][j2];
      c2[threadIdx.x] = t;
    }
  }
}

// ---------------- K1: logits + softmax -> A, asum ----------------
// grid 1024 = 16 b x 64 chunks of 64 positions; block 256 = 4 waves.
// Wave w handles channels [w*128, (w+1)*128) for all 64 positions; LDS reduce.
__global__ __launch_bounds__(256) void logits_kernel(
    const float* __restrict__ x, const float* __restrict__ cwt,
    const float* __restrict__ c2, const float* __restrict__ scale,
    float* __restrict__ A, float* __restrict__ asum) {
  const int b = blockIdx.x >> 6;
  const int n0 = (blockIdx.x & 63) << 6;
  const int lane = threadIdx.x & 63;
  const int w = threadIdx.x >> 6;
  const float* xp = x + (size_t)b * CC * NN + n0 + lane;
  const int cbase = w * 128;

  float acc[KK];
#pragma unroll
  for (int k = 0; k < KK; ++k) acc[k] = 0.f;
  float x2 = 0.f;

  constexpr int G = 8;
  float xv[G], xn[G];
#pragma unroll
  for (int j = 0; j < G; ++j) xv[j] = xp[(size_t)(cbase + j) * NN];

  for (int cg = 0; cg < 128; cg += G) {
    if (cg + G < 128) {
#pragma unroll
      for (int j = 0; j < G; ++j) xn[j] = xp[(size_t)(cbase + cg + G + j) * NN];
    }
#pragma unroll
    for (int j = 0; j < G; ++j) {
      float v = xv[j];
      x2 = fmaf(v, v, x2);
      const float* cwp = cwt + (cbase + cg + j) * KK;  // wave-uniform -> s_load
#pragma unroll
      for (int k = 0; k < KK; ++k) acc[k] = fmaf(v, cwp[k], acc[k]);
    }
#pragma unroll
    for (int j = 0; j < G; ++j) xv[j] = xn[j];
  }

  // cross-wave reduction in LDS. Sp[w][p][33] pitch-33 -> (p+k)%32 banks.
  __shared__ float Sp[4 * 64 * 33];  // 33792 B
  __shared__ float Sx[4 * 65];       // x2 partials
  {
    float* sp = Sp + (w * 64 + lane) * 33;
#pragma unroll
    for (int k = 0; k < KK; ++k) sp[k] = acc[k];
    Sx[w * 65 + lane] = x2;
  }
  __syncthreads();

  // phase A: sum 4 wave-partials; thread t -> (p = t&63, kgroup = t>>6 of 8 k)
  {
    const int p = threadIdx.x & 63;
    const int kg = threadIdx.x >> 6;
#pragma unroll
    for (int j = 0; j < 8; ++j) {
      int k = kg * 8 + j;
      float s = Sp[(0 * 64 + p) * 33 + k] + Sp[(1 * 64 + p) * 33 + k] +
                Sp[(2 * 64 + p) * 33 + k] + Sp[(3 * 64 + p) * 33 + k];
      Sp[(0 * 64 + p) * 33 + k] = s;
    }
    if (kg == 0) Sx[p] = Sx[p] + Sx[65 + p] + Sx[2 * 65 + p] + Sx[3 * 65 + p];
  }
  __syncthreads();

  // phase B: wave 0 does softmax for its 64 positions
  if (threadIdx.x < 64) {
    const int p = lane;
    const float xx = Sx[p];
    float l[KK];
    float m = -INFINITY;
#pragma unroll
    for (int k = 0; k < KK; ++k) {
      float d = Sp[p * 33 + k];
      float lg = scale[k] * (xx - 2.f * d + c2[k]);
      l[k] = lg;
      m = fmaxf(m, lg);
    }
    float s = 0.f;
#pragma unroll
    for (int k = 0; k < KK; ++k) {
      float e = __expf(l[k] - m);
      l[k] = e;
      s += e;
    }
    float inv = 1.0f / s;
    float* Ab = A + ((size_t)b * KK) * NN + n0 + p;
#pragma unroll
    for (int k = 0; k < KK; ++k) {
      float a = l[k] * inv;
      l[k] = a;
      Ab[(size_t)k * NN] = a;  // coalesced across p
    }
#pragma unroll
    for (int k = 0; k < KK; ++k) {
      float v = l[k];
      v += __shfl_xor(v, 1);
      v += __shfl_xor(v, 2);
      v += __shfl_xor(v, 4);
      v += __shfl_xor(v, 8);
      v += __shfl_xor(v, 16);
      v += __shfl_xor(v, 32);
      if (p == 0) atomicAdd(&asum[b * KK + k], v);
    }
  }
}

// ---------------- K2: out[b,k,c] += sum_n A[b,k,n]*x[b,c,n] ----------------
// grid 1024 = 16 b x 4 c-chunks(128) x 16 n-chunks(256); block 256 threads.
// Thread tile 4k x 4c: k = kq+8*ik (kq=t&7), c = c0+cq+32*i (cq=t>>3).
// LDS pitch 68: row r starts at bank (r*68)%32 = 4*(r%8) -> reads conflict-free.
constexpr int CT = 128;
constexpr int NT = 256;
constexpr int NS = 64;
constexpr int PITCH = 68;

__global__ __launch_bounds__(256) void agg_kernel(
    const float* __restrict__ x, const float* __restrict__ A,
    float* __restrict__ out) {
  const int b = blockIdx.x >> 6;
  const int rem = blockIdx.x & 63;
  const int c0 = (rem & 3) * CT;
  const int n0 = (rem >> 2) * NT;
  const int t = threadIdx.x;
  const int kq = t & 7;
  const int cq = t >> 3;

  __shared__ float Xl[CT * PITCH];  // 34816 B
  __shared__ float Al[KK * PITCH];  //  8704 B

  float acc[4][4];
#pragma unroll
  for (int ik = 0; ik < 4; ++ik)
#pragma unroll
    for (int i = 0; i < 4; ++i) acc[ik][i] = 0.f;

  const float* xb = x + ((size_t)b * CC + c0) * NN + n0;
  const float* Ab = A + ((size_t)b * KK) * NN + n0;

  for (int ns = 0; ns < NT; ns += NS) {
    __syncthreads();
#pragma unroll
    for (int j = 0; j < 8; ++j) {  // stage X: 128 rows x 16 float4
      int idx = t + 256 * j;
      int row = idx >> 4, col4 = idx & 15;
      float4 v = *(const float4*)(xb + (size_t)row * NN + ns + col4 * 4);
      *(float4*)&Xl[row * PITCH + col4 * 4] = v;
    }
#pragma unroll
    for (int j = 0; j < 2; ++j) {  // stage A: 32 rows x 16 float4
      int idx = t + 256 * j;
      int row = idx >> 4, col4 = idx & 15;
      float4 v = *(const float4*)(Ab + (size_t)row * NN + ns + col4 * 4);
      *(float4*)&Al[row * PITCH + col4 * 4] = v;
    }
    __syncthreads();
#pragma unroll 2
    for (int nn = 0; nn < NS; nn += 4) {
      float4 av[4], xv[4];
#pragma unroll
      for (int ik = 0; ik < 4; ++ik)
        av[ik] = *(const float4*)&Al[(kq + 8 * ik) * PITCH + nn];
#pragma unroll
      for (int i = 0; i < 4; ++i)
        xv[i] = *(const float4*)&Xl[(cq + 32 * i) * PITCH + nn];
#pragma unroll
      for (int ik = 0; ik < 4; ++ik)
#pragma unroll
        for (int i = 0; i < 4; ++i) {
          acc[ik][i] = fmaf(av[ik].x, xv[i].x, acc[ik][i]);
          acc[ik][i] = fmaf(av[ik].y, xv[i].y, acc[ik][i]);
          acc[ik][i] = fmaf(av[ik].z, xv[i].z, acc[ik][i]);
          acc[ik][i] = fmaf(av[ik].w, xv[i].w, acc[ik][i]);
        }
    }
  }

#pragma unroll
  for (int ik = 0; ik < 4; ++ik) {
    int k = kq + 8 * ik;
#pragma unroll
    for (int i = 0; i < 4; ++i) {
      int c = c0 + cq + 32 * i;
      atomicAdd(&out[((size_t)b * KK + k) * CC + c], acc[ik][i]);
    }
  }
}

// ---------------- K3: out -= asum * cw ----------------
__global__ __launch_bounds__(256) void finalize_kernel(
    float* __restrict__ out, const float* __restrict__ asum,
    const float* __restrict__ cw) {
  int idx = blockIdx.x * blockDim.x + threadIdx.x;  // float4 index, 65536 total
  int b = idx >> 12;
  int k = (idx >> 7) & 31;
  int c4 = idx & 127;
  float4 o = ((float4*)out)[idx];
  float4 wv = ((const float4*)cw)[k * 128 + c4];
  float a = asum[b * 32 + k];
  o.x -= a * wv.x;
  o.y -= a * wv.y;
  o.z -= a * wv.z;
  o.w -= a * wv.w;
  ((float4*)out)[idx] = o;
}

extern "C" void kernel_launch(void* const* d_in, const int* in_sizes, int n_in,
                              void* d_out, int out_size, void* d_ws, size_t ws_size,
                              hipStream_t stream) {
  const float* x = (const float*)d_in[0];      // (16,512,64,64)
  const float* cw = (const float*)d_in[1];     // (32,512)
  const float* scale = (const float*)d_in[2];  // (32,)
  float* out = (float*)d_out;                  // (16,32,512)
  float* ws = (float*)d_ws;

  float* cwt = ws;           // 16384
  float* c2 = ws + 16384;    // 32
  float* asum = ws + 16416;  // 512
  float* A = ws + 16928;     // B*K*N = 2097152

  prep_kernel<<<64, 256, 0, stream>>>(cw, cwt, c2, asum, out);
  logits_kernel<<<1024, 256, 0, stream>>>(x, cwt, c2, scale, A, asum);
  agg_kernel<<<1024, 256, 0, stream>>>(x, A, out);
  finalize_kernel<<<256, 256, 0, stream>>>(out, asum, cw);
}

// Round 3
// 275.291 us; speedup vs baseline: 1.4139x; 1.4139x over previous
//
#include <hip/hip_runtime.h>
#include <hip/hip_bf16.h>
#include <math.h>

// Problem: B=16, C=512, N=H*W=4096, K=32
#define BB 16
#define CC 512
#define NN 4096
#define KK 32

typedef __attribute__((ext_vector_type(8))) short short8;
typedef __attribute__((ext_vector_type(4))) float float4v;

static __device__ __forceinline__ unsigned short f2bf(float f) {
  unsigned u = __float_as_uint(f);
  u += 0x7FFF + ((u >> 16) & 1);  // RNE
  return (unsigned short)(u >> 16);
}
static __device__ __forceinline__ float bf2f(unsigned short s) {
  return __uint_as_float(((unsigned)s) << 16);
}

// ws layout (bytes):
//   [0,128)        c2 (32 fp32)
//   [128,32896)    cwt2 (512 c x 32 k) bf16: cwt2[c*32+k] = bf16(cw[k][c])
//   [32896,+4.2MB) A (B,K,N) bf16

// ---------------- K0: prep ----------------
__global__ __launch_bounds__(256) void prep_kernel(
    const float* __restrict__ cw, unsigned short* __restrict__ cwt2,
    float* __restrict__ c2, float* __restrict__ out) {
  int gid = blockIdx.x * 256 + threadIdx.x;  // 16384 threads
  // zero out (B*K*C = 262144 floats = 65536 float4)
  float4v z = {0.f, 0.f, 0.f, 0.f};
  float4v* o4 = (float4v*)out;
#pragma unroll
  for (int j = 0; j < 4; ++j) o4[gid + j * 16384] = z;
  // cwt2: one elem per thread
  {
    int c = gid >> 5, k = gid & 31;
    cwt2[gid] = f2bf(cw[k * CC + c]);
  }
  // c2 on block 0 (fp32 exact)
  __shared__ float c2p[KK][8];
  if (blockIdx.x == 0) {
    int k = threadIdx.x >> 3, j = threadIdx.x & 7;
    const float* row = cw + k * CC + j * 64;
    float s = 0.f;
    for (int i = 0; i < 64; ++i) s = fmaf(row[i], row[i], s);
    c2p[k][j] = s;
    __syncthreads();
    if (threadIdx.x < KK) {
      float t = 0.f;
      for (int j2 = 0; j2 < 8; ++j2) t += c2p[threadIdx.x][j2];
      c2[threadIdx.x] = t;
    }
  }
}

// ---------------- K1: logits + softmax -> A (bf16) ----------------
// grid 256 = 16 b x 16 pos-chunks(256); block 256.
// thread: kq=t&3 -> k in [8kq,8kq+8); pq=t>>2 -> pos 4pq..4pq+3.
// x staged to LDS (fp32, dbuf); cw read from global bf16 (L1-resident, vector).
// softmax via shfl within 4-lane kq-groups; x2 computed fp32-exact.
__global__ __launch_bounds__(256) void logits_kernel(
    const float* __restrict__ x, const unsigned short* __restrict__ cwt2,
    const float* __restrict__ c2g, const float* __restrict__ scale,
    unsigned short* __restrict__ A) {
  const int b = blockIdx.x >> 4;
  const int n0 = (blockIdx.x & 15) << 8;
  const int t = threadIdx.x;
  const int kq = t & 3;
  const int pq = t >> 2;

  __shared__ float Xl[2][8][258];          // 16512 B, dbuf of 8-channel chunks
  __shared__ unsigned short Sm[256][34];   // 17408 B, A exchange (bf16)

  const float* xb = x + (size_t)b * CC * NN + n0;

  float sc[8], cc2[8];
#pragma unroll
  for (int i = 0; i < 8; ++i) {
    sc[i] = scale[8 * kq + i];
    cc2[i] = c2g[8 * kq + i];
  }

  float acc[8][4];
#pragma unroll
  for (int i = 0; i < 8; ++i)
#pragma unroll
    for (int p = 0; p < 4; ++p) acc[i][p] = 0.f;
  float x2[4] = {0.f, 0.f, 0.f, 0.f};

  // stage chunk 0: 8 rows x 256 floats = 512 float4 / 256 thr = 2 each
  float4v pf[2];
#pragma unroll
  for (int j = 0; j < 2; ++j) {
    int f = t + 256 * j;
    int row = f >> 6, c4 = f & 63;
    pf[j] = *(const float4v*)(xb + (size_t)row * NN + c4 * 4);
  }
#pragma unroll
  for (int j = 0; j < 2; ++j) {
    int f = t + 256 * j;
    int row = f >> 6, c4 = f & 63;
    *(float4v*)&Xl[0][row][c4 * 4] = pf[j];
  }
  __syncthreads();

  int cur = 0;
  for (int ch = 0; ch < 64; ++ch) {
    const int cbase = ch * 8;
    if (ch < 63) {
#pragma unroll
      for (int j = 0; j < 2; ++j) {
        int f = t + 256 * j;
        int row = f >> 6, c4 = f & 63;
        pf[j] = *(const float4v*)(xb + (size_t)(cbase + 8 + row) * NN + c4 * 4);
      }
    }
#pragma unroll
    for (int c = 0; c < 8; ++c) {
      float4v xv = *(const float4v*)&Xl[cur][c][4 * pq];
      short8 cwv = *(const short8*)(cwt2 + (size_t)(cbase + c) * 32 + 8 * kq);
      float cf[8];
#pragma unroll
      for (int i = 0; i < 8; ++i) cf[i] = bf2f(((unsigned short*)&cwv)[i]);
      x2[0] = fmaf(xv.x, xv.x, x2[0]);
      x2[1] = fmaf(xv.y, xv.y, x2[1]);
      x2[2] = fmaf(xv.z, xv.z, x2[2]);
      x2[3] = fmaf(xv.w, xv.w, x2[3]);
#pragma unroll
      for (int i = 0; i < 8; ++i) {
        acc[i][0] = fmaf(cf[i], xv.x, acc[i][0]);
        acc[i][1] = fmaf(cf[i], xv.y, acc[i][1]);
        acc[i][2] = fmaf(cf[i], xv.z, acc[i][2]);
        acc[i][3] = fmaf(cf[i], xv.w, acc[i][3]);
      }
    }
    if (ch < 63) {
      int nxt = cur ^ 1;
#pragma unroll
      for (int j = 0; j < 2; ++j) {
        int f = t + 256 * j;
        int row = f >> 6, c4 = f & 63;
        *(float4v*)&Xl[nxt][row][c4 * 4] = pf[j];
      }
      __syncthreads();
      cur = nxt;
    }
  }

  // softmax per position; all-32-k max/sum via shfl over the 4 kq lanes
#pragma unroll
  for (int p = 0; p < 4; ++p) {
    float l[8];
    float m = -INFINITY;
#pragma unroll
    for (int i = 0; i < 8; ++i) {
      float lg = sc[i] * (x2[p] - 2.f * acc[i][p] + cc2[i]);
      l[i] = lg;
      m = fmaxf(m, lg);
    }
    m = fmaxf(m, __shfl_xor(m, 1));
    m = fmaxf(m, __shfl_xor(m, 2));
    float s = 0.f;
#pragma unroll
    for (int i = 0; i < 8; ++i) {
      float e = __expf(l[i] - m);
      l[i] = e;
      s += e;
    }
    s += __shfl_xor(s, 1);
    s += __shfl_xor(s, 2);
    float inv = 1.0f / s;
    const int pos = 4 * pq + p;
#pragma unroll
    for (int i = 0; i < 8; ++i) Sm[pos][8 * kq + i] = f2bf(l[i] * inv);
  }
  __syncthreads();

  // coalesced A store: thread t handles position n0+t for all k
#pragma unroll
  for (int k = 0; k < KK; ++k) {
    A[((size_t)(b * KK + k)) * NN + n0 + t] = Sm[t][k];
  }
}

// ---------------- K2: out[b,k,c] += sum_n A[k,n]*x[c,n]  (bf16 MFMA) ----------------
// grid 256 = 16 b x 16 n-chunks(256); block 256 = 4 waves.
// wave w: c-range [128w,128w+128) = 8 c-tiles x 2 m-tiles (k 0-15,16-31).
// Fragments loaded straight from global (n-contiguous); x cvt fp32->bf16 in-reg.
__global__ __launch_bounds__(256) void agg_kernel(
    const float* __restrict__ x, const unsigned short* __restrict__ A,
    float* __restrict__ out) {
  const int b = blockIdx.x >> 4;
  const int n0 = (blockIdx.x & 15) << 8;
  const int t = threadIdx.x;
  const int w = t >> 6;
  const int l = t & 63;
  const int l15 = l & 15;
  const int q = l >> 4;
  const int cw0 = 128 * w;

  float4v acc[8][2];
#pragma unroll
  for (int ct = 0; ct < 8; ++ct)
#pragma unroll
    for (int m = 0; m < 2; ++m) acc[ct][m] = (float4v){0.f, 0.f, 0.f, 0.f};

  const unsigned short* Ab = A + (size_t)b * KK * NN;
  const float* xb = x + (size_t)b * CC * NN;

  for (int s = 0; s < 8; ++s) {
    const int nb = n0 + s * 32 + q * 8;
    // A-frags: A[m = l&15 (+16)][kdim = n, 8 consecutive]
    short8 a0 = *(const short8*)(Ab + (size_t)l15 * NN + nb);
    short8 a1 = *(const short8*)(Ab + (size_t)(16 + l15) * NN + nb);
#pragma unroll
    for (int ct = 0; ct < 8; ++ct) {
      const int c = cw0 + 16 * ct + l15;
      const float* xp = xb + (size_t)c * NN + nb;
      float4v x0 = *(const float4v*)xp;
      float4v x1 = *(const float4v*)(xp + 4);
      short8 bv;
      bv[0] = (short)f2bf(x0.x);
      bv[1] = (short)f2bf(x0.y);
      bv[2] = (short)f2bf(x0.z);
      bv[3] = (short)f2bf(x0.w);
      bv[4] = (short)f2bf(x1.x);
      bv[5] = (short)f2bf(x1.y);
      bv[6] = (short)f2bf(x1.z);
      bv[7] = (short)f2bf(x1.w);
      acc[ct][0] = __builtin_amdgcn_mfma_f32_16x16x32_bf16(a0, bv, acc[ct][0], 0, 0, 0);
      acc[ct][1] = __builtin_amdgcn_mfma_f32_16x16x32_bf16(a1, bv, acc[ct][1], 0, 0, 0);
    }
  }

  // C/D layout: col(c) = l&15, row(k) = 4*(l>>4)+r (+16 for m-tile 1)
#pragma unroll
  for (int ct = 0; ct < 8; ++ct) {
    const int c = cw0 + 16 * ct + l15;
#pragma unroll
    for (int m = 0; m < 2; ++m)
#pragma unroll
      for (int r = 0; r < 4; ++r) {
        int k = 16 * m + 4 * q + r;
        atomicAdd(&out[((size_t)(b * KK + k)) * CC + c], acc[ct][m][r]);
      }
  }
}

// ---------------- K3: out -= asum*cw, asum = sum_n A[b,k,n] ----------------
__global__ __launch_bounds__(256) void finalize_kernel(
    float* __restrict__ out, const unsigned short* __restrict__ A,
    const float* __restrict__ cw) {
  const int bk = blockIdx.x;  // b*32+k
  const int k = bk & 31;
  const int t = threadIdx.x;
  const unsigned short* Ar = A + (size_t)bk * NN;

  float s = 0.f;
#pragma unroll
  for (int j = 0; j < 2; ++j) {
    short8 v = *(const short8*)(Ar + t * 16 + j * 8);
#pragma unroll
    for (int i = 0; i < 8; ++i) s += bf2f(((unsigned short*)&v)[i]);
  }
  s += __shfl_xor(s, 1);
  s += __shfl_xor(s, 2);
  s += __shfl_xor(s, 4);
  s += __shfl_xor(s, 8);
  s += __shfl_xor(s, 16);
  s += __shfl_xor(s, 32);

  __shared__ float red[4];
  __shared__ float asums;
  if ((t & 63) == 0) red[t >> 6] = s;
  __syncthreads();
  if (t == 0) asums = red[0] + red[1] + red[2] + red[3];
  __syncthreads();
  const float asum = asums;

#pragma unroll
  for (int j = 0; j < 2; ++j) {
    int c = t + 256 * j;
    out[(size_t)bk * CC + c] -= asum * cw[k * CC + c];
  }
}

extern "C" void kernel_launch(void* const* d_in, const int* in_sizes, int n_in,
                              void* d_out, int out_size, void* d_ws, size_t ws_size,
                              hipStream_t stream) {
  const float* x = (const float*)d_in[0];      // (16,512,64,64)
  const float* cw = (const float*)d_in[1];     // (32,512)
  const float* scale = (const float*)d_in[2];  // (32,)
  float* out = (float*)d_out;                  // (16,32,512)
  char* ws = (char*)d_ws;

  float* c2 = (float*)ws;                            // 128 B
  unsigned short* cwt2 = (unsigned short*)(ws + 128);  // 32 KB
  unsigned short* A = (unsigned short*)(ws + 32896);   // 4.2 MB

  prep_kernel<<<64, 256, 0, stream>>>(cw, cwt2, c2, out);
  logits_kernel<<<256, 256, 0, stream>>>(x, cwt2, c2, scale, A);
  agg_kernel<<<256, 256, 0, stream>>>(x, A, out);
  finalize_kernel<<<512, 256, 0, stream>>>(out, A, cw);
}

// Round 4
// 244.082 us; speedup vs baseline: 1.5947x; 1.1279x over previous
//
#include <hip/hip_runtime.h>
#include <hip/hip_bf16.h>
#include <math.h>

// Problem: B=16, C=512, N=H*W=4096, K=32
#define BB 16
#define CC 512
#define NN 4096
#define KK 32

typedef __attribute__((ext_vector_type(8))) short short8;
typedef __attribute__((ext_vector_type(4))) float float4v;

static __device__ __forceinline__ unsigned short f2bf(float f) {
  unsigned u = __float_as_uint(f);
  u += 0x7FFF + ((u >> 16) & 1);  // RNE
  return (unsigned short)(u >> 16);
}

// ws layout (bytes):
//   [0,128)          c2   (32 fp32)
//   [128,32896)      cwB  (32 k x 512 c) bf16 (same k-major layout as cw)
//   [32896,34944)    asum (B*K fp32)
//   [34944,+4MB)     A    (B,K,N) bf16

// ---------------- K0: prep ----------------
__global__ __launch_bounds__(256) void prep_kernel(
    const float* __restrict__ cw, unsigned short* __restrict__ cwB,
    float* __restrict__ c2, float* __restrict__ asum, float* __restrict__ out) {
  int gid = blockIdx.x * 256 + threadIdx.x;  // 16384 threads
  // zero out (B*K*C = 262144 floats = 65536 float4) for agg atomics
  float4v z = {0.f, 0.f, 0.f, 0.f};
  float4v* o4 = (float4v*)out;
#pragma unroll
  for (int j = 0; j < 4; ++j) o4[gid + j * 16384] = z;
  if (gid < BB * KK) asum[gid] = 0.f;
  cwB[gid] = f2bf(cw[gid]);  // elementwise, layout preserved
  // c2 exact fp32
  __shared__ float c2p[KK][8];
  if (blockIdx.x == 0) {
    int k = threadIdx.x >> 3, j = threadIdx.x & 7;
    const float* row = cw + k * CC + j * 64;
    float s = 0.f;
    for (int i = 0; i < 64; ++i) s = fmaf(row[i], row[i], s);
    c2p[k][j] = s;
    __syncthreads();
    if (threadIdx.x < KK) {
      float t = 0.f;
      for (int j2 = 0; j2 < 8; ++j2) t += c2p[threadIdx.x][j2];
      c2[threadIdx.x] = t;
    }
  }
}

// ---------------- K1: logits via MFMA + softmax -> A (bf16), asum ----------------
// grid 1024 = 16 b x 64 n-chunks(64); block 256 = 4 waves.
// Stage x[512c x 64n] -> LDS bf16 (pitch 68), x2 fp32-exact during staging.
// Pass 1: wave w = n-tile; D[m=n][col=k]; A-frag = x^T (u16 LDS reads),
// B-frag = cwB (global, L1-hot). Softmax cross-lane: k lives on l15 lanes.
__global__ __launch_bounds__(256, 2) void logits_kernel(
    const float* __restrict__ x, const unsigned short* __restrict__ cwB,
    const float* __restrict__ c2g, const float* __restrict__ scale,
    unsigned short* __restrict__ A, float* __restrict__ asum) {
  const int b = blockIdx.x >> 6;
  const int n0 = (blockIdx.x & 63) << 6;
  const int t = threadIdx.x;

  __shared__ unsigned short Xl[512][68];  // 69632 B
  __shared__ float Sx2p[16][68];          // 4352 B
  __shared__ float Sx2[64];

  const float* xb = x + (size_t)b * CC * NN + n0;

  // ---- staging: thread (cr=t>>4, f4=t&15) covers c = cr+16i, n = 4f4..4f4+3
  {
    const int f4 = t & 15;
    const int cr = t >> 4;
    float x2p0 = 0.f, x2p1 = 0.f, x2p2 = 0.f, x2p3 = 0.f;
    for (int cc = 0; cc < 512; cc += 64) {
      float4v v[4];
#pragma unroll
      for (int i = 0; i < 4; ++i)
        v[i] = *(const float4v*)(xb + (size_t)(cc + 16 * i + cr) * NN + 4 * f4);
#pragma unroll
      for (int i = 0; i < 4; ++i) {
        x2p0 = fmaf(v[i].x, v[i].x, x2p0);
        x2p1 = fmaf(v[i].y, v[i].y, x2p1);
        x2p2 = fmaf(v[i].z, v[i].z, x2p2);
        x2p3 = fmaf(v[i].w, v[i].w, x2p3);
        unsigned short h0 = f2bf(v[i].x), h1 = f2bf(v[i].y);
        unsigned short h2 = f2bf(v[i].z), h3 = f2bf(v[i].w);
        unsigned p0 = (unsigned)h0 | ((unsigned)h1 << 16);
        unsigned p1 = (unsigned)h2 | ((unsigned)h3 << 16);
        uint2 pk = make_uint2(p0, p1);
        *(uint2*)&Xl[cc + 16 * i + cr][4 * f4] = pk;
      }
    }
    Sx2p[cr][4 * f4 + 0] = x2p0;
    Sx2p[cr][4 * f4 + 1] = x2p1;
    Sx2p[cr][4 * f4 + 2] = x2p2;
    Sx2p[cr][4 * f4 + 3] = x2p3;
  }
  __syncthreads();
  if (t < 64) {
    float s = 0.f;
#pragma unroll
    for (int r = 0; r < 16; ++r) s += Sx2p[r][t];
    Sx2[t] = s;
  }
  __syncthreads();

  // ---- pass 1: MFMA xc
  const int w = t >> 6;
  const int l = t & 63;
  const int l15 = l & 15;
  const int q = l >> 4;
  const int nrow = w * 16 + l15;  // n used for A-frag (m index)

  float4v acc0 = {0.f, 0.f, 0.f, 0.f};
  float4v acc1 = {0.f, 0.f, 0.f, 0.f};

  for (int cs = 0; cs < 512; cs += 32) {
    const int cb = cs + q * 8;
    short8 af;
#pragma unroll
    for (int j = 0; j < 8; ++j) af[j] = (short)Xl[cb + j][nrow];
    short8 b0 = *(const short8*)(cwB + (size_t)l15 * CC + cb);
    short8 b1 = *(const short8*)(cwB + (size_t)(16 + l15) * CC + cb);
    acc0 = __builtin_amdgcn_mfma_f32_16x16x32_bf16(af, b0, acc0, 0, 0, 0);
    acc1 = __builtin_amdgcn_mfma_f32_16x16x32_bf16(af, b1, acc1, 0, 0, 0);
  }
  // lane now holds xc for n = w*16 + 4q + r, k = l15 (acc0) / 16+l15 (acc1)

  const float sc0 = scale[l15], sc1 = scale[16 + l15];
  const float cc0 = c2g[l15], cc1 = c2g[16 + l15];

  float a0[4], a1[4];
#pragma unroll
  for (int r = 0; r < 4; ++r) {
    const float xx = Sx2[w * 16 + 4 * q + r];
    float l0 = sc0 * (xx - 2.f * acc0[r] + cc0);
    float l1 = sc1 * (xx - 2.f * acc1[r] + cc1);
    float m = fmaxf(l0, l1);
    m = fmaxf(m, __shfl_xor(m, 1));
    m = fmaxf(m, __shfl_xor(m, 2));
    m = fmaxf(m, __shfl_xor(m, 4));
    m = fmaxf(m, __shfl_xor(m, 8));
    float e0 = __expf(l0 - m), e1 = __expf(l1 - m);
    float s = e0 + e1;
    s += __shfl_xor(s, 1);
    s += __shfl_xor(s, 2);
    s += __shfl_xor(s, 4);
    s += __shfl_xor(s, 8);
    float inv = 1.0f / s;
    a0[r] = e0 * inv;
    a1[r] = e1 * inv;
  }

  // ---- store A bf16: lane's 4 n are contiguous (w*16 + 4q + r)
  {
    unsigned p00 = (unsigned)f2bf(a0[0]) | ((unsigned)f2bf(a0[1]) << 16);
    unsigned p01 = (unsigned)f2bf(a0[2]) | ((unsigned)f2bf(a0[3]) << 16);
    unsigned p10 = (unsigned)f2bf(a1[0]) | ((unsigned)f2bf(a1[1]) << 16);
    unsigned p11 = (unsigned)f2bf(a1[2]) | ((unsigned)f2bf(a1[3]) << 16);
    unsigned short* A0 = A + ((size_t)(b * KK + l15)) * NN + n0 + w * 16 + 4 * q;
    unsigned short* A1 = A + ((size_t)(b * KK + 16 + l15)) * NN + n0 + w * 16 + 4 * q;
    *(uint2*)A0 = make_uint2(p00, p01);
    *(uint2*)A1 = make_uint2(p10, p11);
  }

  // ---- asum: reduce lane's 4 n, then over q (xor 16,32), one atomic per k
  {
    float s0 = a0[0] + a0[1] + a0[2] + a0[3];
    float s1 = a1[0] + a1[1] + a1[2] + a1[3];
    s0 += __shfl_xor(s0, 16);
    s0 += __shfl_xor(s0, 32);
    s1 += __shfl_xor(s1, 16);
    s1 += __shfl_xor(s1, 32);
    if (q == 0) {
      atomicAdd(&asum[b * KK + l15], s0);
      atomicAdd(&asum[b * KK + 16 + l15], s1);
    }
  }
}

// ---------------- K2: out[b,k,c] += sum_n A[k,n]*x[c,n]  (bf16 MFMA) ----------------
// grid 1024 = 16 b x 4 c-groups(128) x 16 n-chunks(256); block 256 = 4 waves.
// wave w: c-range [cg*128 + 32w, +32) = 2 c-tiles x 2 m-tiles.
__global__ __launch_bounds__(256, 4) void agg_kernel(
    const float* __restrict__ x, const unsigned short* __restrict__ A,
    float* __restrict__ out) {
  const int b = blockIdx.x >> 6;
  const int cg = (blockIdx.x >> 4) & 3;
  const int n0 = (blockIdx.x & 15) << 8;
  const int t = threadIdx.x;
  const int w = t >> 6;
  const int l = t & 63;
  const int l15 = l & 15;
  const int q = l >> 4;
  const int cw0 = cg * 128 + 32 * w;

  float4v acc[2][2];  // [ct][m]
#pragma unroll
  for (int ct = 0; ct < 2; ++ct)
#pragma unroll
    for (int m = 0; m < 2; ++m) acc[ct][m] = (float4v){0.f, 0.f, 0.f, 0.f};

  const unsigned short* Ab = A + (size_t)b * KK * NN;
  const float* xb = x + (size_t)b * CC * NN;

  for (int s = 0; s < 8; ++s) {
    const int nb = n0 + s * 32 + q * 8;
    short8 a0 = *(const short8*)(Ab + (size_t)l15 * NN + nb);
    short8 a1 = *(const short8*)(Ab + (size_t)(16 + l15) * NN + nb);
#pragma unroll
    for (int ct = 0; ct < 2; ++ct) {
      const int c = cw0 + 16 * ct + l15;
      const float* xp = xb + (size_t)c * NN + nb;
      float4v x0 = *(const float4v*)xp;
      float4v x1 = *(const float4v*)(xp + 4);
      short8 bv;
      bv[0] = (short)f2bf(x0.x);
      bv[1] = (short)f2bf(x0.y);
      bv[2] = (short)f2bf(x0.z);
      bv[3] = (short)f2bf(x0.w);
      bv[4] = (short)f2bf(x1.x);
      bv[5] = (short)f2bf(x1.y);
      bv[6] = (short)f2bf(x1.z);
      bv[7] = (short)f2bf(x1.w);
      acc[ct][0] = __builtin_amdgcn_mfma_f32_16x16x32_bf16(a0, bv, acc[ct][0], 0, 0, 0);
      acc[ct][1] = __builtin_amdgcn_mfma_f32_16x16x32_bf16(a1, bv, acc[ct][1], 0, 0, 0);
    }
  }

  // C/D: col(c)=l15, row(k)=4q+r (+16 for m=1)
#pragma unroll
  for (int ct = 0; ct < 2; ++ct) {
    const int c = cw0 + 16 * ct + l15;
#pragma unroll
    for (int m = 0; m < 2; ++m)
#pragma unroll
      for (int r = 0; r < 4; ++r) {
        int k = 16 * m + 4 * q + r;
        atomicAdd(&out[((size_t)(b * KK + k)) * CC + c], acc[ct][m][r]);
      }
  }
}

// ---------------- K3: out -= asum * cw ----------------
__global__ __launch_bounds__(256) void finalize_kernel(
    float* __restrict__ out, const float* __restrict__ asum,
    const float* __restrict__ cw) {
  int idx = blockIdx.x * 256 + threadIdx.x;  // float4 index, 65536 total
  int b = idx >> 12;
  int k = (idx >> 7) & 31;
  int c4 = idx & 127;
  float4v o = ((float4v*)out)[idx];
  float4v wv = ((const float4v*)cw)[k * 128 + c4];
  float a = asum[b * KK + k];
  o.x -= a * wv.x;
  o.y -= a * wv.y;
  o.z -= a * wv.z;
  o.w -= a * wv.w;
  ((float4v*)out)[idx] = o;
}

extern "C" void kernel_launch(void* const* d_in, const int* in_sizes, int n_in,
                              void* d_out, int out_size, void* d_ws, size_t ws_size,
                              hipStream_t stream) {
  const float* x = (const float*)d_in[0];      // (16,512,64,64)
  const float* cw = (const float*)d_in[1];     // (32,512)
  const float* scale = (const float*)d_in[2];  // (32,)
  float* out = (float*)d_out;                  // (16,32,512)
  char* ws = (char*)d_ws;

  float* c2 = (float*)ws;                              // 128 B
  unsigned short* cwB = (unsigned short*)(ws + 128);   // 32 KB
  float* asum = (float*)(ws + 32896);                  // 2 KB
  unsigned short* A = (unsigned short*)(ws + 34944);   // 4 MB

  prep_kernel<<<64, 256, 0, stream>>>(cw, cwB, c2, asum, out);
  logits_kernel<<<1024, 256, 0, stream>>>(x, cwB, c2, scale, A, asum);
  agg_kernel<<<1024, 256, 0, stream>>>(x, A, out);
  finalize_kernel<<<256, 256, 0, stream>>>(out, asum, cw);
}

// Round 5
// 233.033 us; speedup vs baseline: 1.6703x; 1.0474x over previous
//
#include <hip/hip_runtime.h>
#include <hip/hip_bf16.h>
#include <math.h>

// Problem: B=16, C=512, N=H*W=4096, K=32
#define BB 16
#define CC 512
#define NN 4096
#define KK 32

typedef __attribute__((ext_vector_type(8))) short short8;
typedef __attribute__((ext_vector_type(4))) float float4v;

static __device__ __forceinline__ unsigned short f2bf(float f) {
  unsigned u = __float_as_uint(f);
  u += 0x7FFF + ((u >> 16) & 1);  // RNE
  return (unsigned short)(u >> 16);
}

// ws layout (bytes):
//   [0,128)       c2   (32 fp32)
//   [128,32896)   cwB  (32 k x 512 c) bf16 (k-major, same layout as cw)
//   [32896,34944) asum (B*K fp32)

// ---------------- K0: prep ----------------
__global__ __launch_bounds__(256) void prep_kernel(
    const float* __restrict__ cw, unsigned short* __restrict__ cwB,
    float* __restrict__ c2, float* __restrict__ asum, float* __restrict__ out) {
  int gid = blockIdx.x * 256 + threadIdx.x;  // 16384 threads
  // zero out (B*K*C = 262144 floats = 65536 float4) for fused atomics
  float4v z = {0.f, 0.f, 0.f, 0.f};
  float4v* o4 = (float4v*)out;
#pragma unroll
  for (int j = 0; j < 4; ++j) o4[gid + j * 16384] = z;
  if (gid < BB * KK) asum[gid] = 0.f;
  cwB[gid] = f2bf(cw[gid]);  // elementwise, layout preserved
  // c2 exact fp32
  __shared__ float c2p[KK][8];
  if (blockIdx.x == 0) {
    int k = threadIdx.x >> 3, j = threadIdx.x & 7;
    const float* row = cw + k * CC + j * 64;
    float s = 0.f;
    for (int i = 0; i < 64; ++i) s = fmaf(row[i], row[i], s);
    c2p[k][j] = s;
    __syncthreads();
    if (threadIdx.x < KK) {
      float t = 0.f;
      for (int j2 = 0; j2 < 8; ++j2) t += c2p[threadIdx.x][j2];
      c2[threadIdx.x] = t;
    }
  }
}

// ---------------- K1: fused logits->softmax->aggregate ----------------
// grid 512 = 16 b x 32 chunks(128 n); block 256 = 4 waves; 2 sub-tiles of 64 n.
// Per sub: stage x (bf16, Xl[512][72], 16B-aligned rows) + fp32 x2;
// phase1 MFMA: D[n][k] = x.cw^T (A-frag = Xl columns u16, B = cwB global);
// softmax in-wave (k on l15 lanes); A-weights -> As[32][72] LDS;
// phase2 MFMA: D[k][c] += A.x^T, both frags contiguous b128 LDS reads.
// acc persists across subs; epilogue: atomicAdd out tile + asum.
#define XP 72
__global__ __launch_bounds__(256, 2) void fused_kernel(
    const float* __restrict__ x, const unsigned short* __restrict__ cwB,
    const float* __restrict__ c2g, const float* __restrict__ scale,
    float* __restrict__ out, float* __restrict__ asum) {
  const int b = blockIdx.x >> 5;
  const int chunk = blockIdx.x & 31;
  const int t = threadIdx.x;
  const int w = t >> 6;
  const int l = t & 63;
  const int l15 = l & 15;
  const int q = l >> 4;

  __shared__ char smem[512 * XP * 2 + 32 * XP * 2 + 256];  // 78592 B
  unsigned short* Xl = (unsigned short*)smem;               // [512][72] u16
  unsigned short* As = (unsigned short*)(smem + 512 * XP * 2);  // [32][72] u16
  float* Sx2p = (float*)(smem + 512 * XP * 2);              // alias As: [16][68]
  float* Sx2 = (float*)(smem + 512 * XP * 2 + 32 * XP * 2); // [64]

  const float* xb0 = x + (size_t)b * CC * NN + chunk * 128;

  const float sc0 = scale[l15], sc1 = scale[16 + l15];
  const float cc0 = c2g[l15], cc1 = c2g[16 + l15];

  float4v acc[8][2];
#pragma unroll
  for (int ct = 0; ct < 8; ++ct)
#pragma unroll
    for (int m = 0; m < 2; ++m) acc[ct][m] = (float4v){0.f, 0.f, 0.f, 0.f};
  float s0acc = 0.f, s1acc = 0.f;

  const int f4 = t & 15;   // staging: n = 4*f4 .. 4*f4+3
  const int cr = t >> 4;   // staging: c = cr + 16*i

  for (int sub = 0; sub < 2; ++sub) {
    const float* xb = xb0 + sub * 64;

    // ---- stage x -> Xl bf16, accumulate fp32 x2 partials
    {
      float4v x2p = {0.f, 0.f, 0.f, 0.f};
#pragma unroll 8
      for (int i = 0; i < 32; ++i) {
        const int c = cr + 16 * i;
        float4v v = *(const float4v*)(xb + (size_t)c * NN + 4 * f4);
        x2p.x = fmaf(v.x, v.x, x2p.x);
        x2p.y = fmaf(v.y, v.y, x2p.y);
        x2p.z = fmaf(v.z, v.z, x2p.z);
        x2p.w = fmaf(v.w, v.w, x2p.w);
        unsigned p0 = (unsigned)f2bf(v.x) | ((unsigned)f2bf(v.y) << 16);
        unsigned p1 = (unsigned)f2bf(v.z) | ((unsigned)f2bf(v.w) << 16);
        *(uint2*)&Xl[c * XP + 4 * f4] = make_uint2(p0, p1);
      }
      *(float4v*)&Sx2p[cr * 68 + 4 * f4] = x2p;
    }
    __syncthreads();
    if (t < 64) {
      float s = 0.f;
#pragma unroll
      for (int r = 0; r < 16; ++r) s += Sx2p[r * 68 + t];
      Sx2[t] = s;
    }
    __syncthreads();

    // ---- phase 1: xc via MFMA. D[m=n (w*16+4q+r)][col=k (l15 / 16+l15)]
    float4v p0 = {0.f, 0.f, 0.f, 0.f};
    float4v p1 = {0.f, 0.f, 0.f, 0.f};
    const int nrow = w * 16 + l15;
    for (int cs = 0; cs < 512; cs += 32) {
      const int cb = cs + q * 8;
      short8 af;
#pragma unroll
      for (int j = 0; j < 8; ++j) af[j] = (short)Xl[(cb + j) * XP + nrow];
      short8 b0 = *(const short8*)(cwB + (size_t)l15 * CC + cb);
      short8 b1 = *(const short8*)(cwB + (size_t)(16 + l15) * CC + cb);
      p0 = __builtin_amdgcn_mfma_f32_16x16x32_bf16(af, b0, p0, 0, 0, 0);
      p1 = __builtin_amdgcn_mfma_f32_16x16x32_bf16(af, b1, p1, 0, 0, 0);
    }

    // ---- softmax per n (lane row r): k spread over l15 lanes
    float a0[4], a1[4];
#pragma unroll
    for (int r = 0; r < 4; ++r) {
      const float xx = Sx2[w * 16 + 4 * q + r];
      float l0 = sc0 * (xx - 2.f * p0[r] + cc0);
      float l1 = sc1 * (xx - 2.f * p1[r] + cc1);
      float m = fmaxf(l0, l1);
      m = fmaxf(m, __shfl_xor(m, 1));
      m = fmaxf(m, __shfl_xor(m, 2));
      m = fmaxf(m, __shfl_xor(m, 4));
      m = fmaxf(m, __shfl_xor(m, 8));
      float e0 = __expf(l0 - m), e1 = __expf(l1 - m);
      float s = e0 + e1;
      s += __shfl_xor(s, 1);
      s += __shfl_xor(s, 2);
      s += __shfl_xor(s, 4);
      s += __shfl_xor(s, 8);
      float inv = 1.0f / s;
      a0[r] = e0 * inv;
      a1[r] = e1 * inv;
    }
    s0acc += a0[0] + a0[1] + a0[2] + a0[3];
    s1acc += a1[0] + a1[1] + a1[2] + a1[3];

    // ---- A-weights -> As[k][n] (safe: Sx2p alias last read before sync #2)
    {
      unsigned p00 = (unsigned)f2bf(a0[0]) | ((unsigned)f2bf(a0[1]) << 16);
      unsigned p01 = (unsigned)f2bf(a0[2]) | ((unsigned)f2bf(a0[3]) << 16);
      unsigned p10 = (unsigned)f2bf(a1[0]) | ((unsigned)f2bf(a1[1]) << 16);
      unsigned p11 = (unsigned)f2bf(a1[2]) | ((unsigned)f2bf(a1[3]) << 16);
      const int nc = w * 16 + 4 * q;
      *(uint2*)&As[l15 * XP + nc] = make_uint2(p00, p01);
      *(uint2*)&As[(16 + l15) * XP + nc] = make_uint2(p10, p11);
    }
    __syncthreads();

    // ---- phase 2: out_tile[k][c] += A . x^T  (contraction over 64 n)
    // wave w: c in [w*128, w*128+128) = 8 tiles; m-tiles k 0-15 / 16-31.
#pragma unroll
    for (int s = 0; s < 2; ++s) {
      const int nb = s * 32 + q * 8;
      short8 am0 = *(const short8*)&As[l15 * XP + nb];
      short8 am1 = *(const short8*)&As[(16 + l15) * XP + nb];
#pragma unroll
      for (int ct = 0; ct < 8; ++ct) {
        const int c = w * 128 + ct * 16 + l15;
        short8 bx = *(const short8*)&Xl[c * XP + nb];
        acc[ct][0] = __builtin_amdgcn_mfma_f32_16x16x32_bf16(am0, bx, acc[ct][0], 0, 0, 0);
        acc[ct][1] = __builtin_amdgcn_mfma_f32_16x16x32_bf16(am1, bx, acc[ct][1], 0, 0, 0);
      }
    }
    __syncthreads();  // protect Xl/As before next sub's staging
  }

  // ---- epilogue: D col=l15 -> c, row=4q+r -> k_local (+16m)
#pragma unroll
  for (int ct = 0; ct < 8; ++ct) {
    const int c = w * 128 + ct * 16 + l15;
#pragma unroll
    for (int m = 0; m < 2; ++m)
#pragma unroll
      for (int r = 0; r < 4; ++r) {
        int k = 16 * m + 4 * q + r;
        atomicAdd(&out[((size_t)(b * KK + k)) * CC + c], acc[ct][m][r]);
      }
  }
  // asum: reduce over q (n-rows) lanes; l15 lanes hold distinct k
  s0acc += __shfl_xor(s0acc, 16);
  s0acc += __shfl_xor(s0acc, 32);
  s1acc += __shfl_xor(s1acc, 16);
  s1acc += __shfl_xor(s1acc, 32);
  if (q == 0) {
    atomicAdd(&asum[b * KK + l15], s0acc);
    atomicAdd(&asum[b * KK + 16 + l15], s1acc);
  }
}

// ---------------- K2: out -= asum * cw ----------------
__global__ __launch_bounds__(256) void finalize_kernel(
    float* __restrict__ out, const float* __restrict__ asum,
    const float* __restrict__ cw) {
  int idx = blockIdx.x * 256 + threadIdx.x;  // float4 index, 65536 total
  int b = idx >> 12;
  int k = (idx >> 7) & 31;
  int c4 = idx & 127;
  float4v o = ((float4v*)out)[idx];
  float4v wv = ((const float4v*)cw)[k * 128 + c4];
  float a = asum[b * KK + k];
  o.x -= a * wv.x;
  o.y -= a * wv.y;
  o.z -= a * wv.z;
  o.w -= a * wv.w;
  ((float4v*)out)[idx] = o;
}

extern "C" void kernel_launch(void* const* d_in, const int* in_sizes, int n_in,
                              void* d_out, int out_size, void* d_ws, size_t ws_size,
                              hipStream_t stream) {
  const float* x = (const float*)d_in[0];      // (16,512,64,64)
  const float* cw = (const float*)d_in[1];     // (32,512)
  const float* scale = (const float*)d_in[2];  // (32,)
  float* out = (float*)d_out;                  // (16,32,512)
  char* ws = (char*)d_ws;

  float* c2 = (float*)ws;                             // 128 B
  unsigned short* cwB = (unsigned short*)(ws + 128);  // 32 KB
  float* asum = (float*)(ws + 32896);                 // 2 KB

  prep_kernel<<<64, 256, 0, stream>>>(cw, cwB, c2, asum, out);
  fused_kernel<<<512, 256, 0, stream>>>(x, cwB, c2, scale, out, asum);
  finalize_kernel<<<256, 256, 0, stream>>>(out, asum, cw);
}

// Round 6
// 228.248 us; speedup vs baseline: 1.7053x; 1.0210x over previous
//
#include <hip/hip_runtime.h>
#include <hip/hip_bf16.h>
#include <math.h>

// Problem: B=16, C=512, N=H*W=4096, K=32
#define BB 16
#define CC 512
#define NN 4096
#define KK 32

typedef __attribute__((ext_vector_type(8))) short short8;
typedef __attribute__((ext_vector_type(4))) float float4v;

static __device__ __forceinline__ unsigned short f2bf(float f) {
  unsigned u = __float_as_uint(f);
  u += 0x7FFF + ((u >> 16) & 1);  // RNE
  return (unsigned short)(u >> 16);
}

// ws layout (bytes):
//   [0,128)        c2   (32 fp32)
//   [128,32896)    cwP  (32 k x 512 c) bf16, c-PERMUTED within 32-blocks:
//                  cwP[k][cs+8q+j] = cw[k][cs + 2q + (j&1) + 8*(j>>1)]
//   [32896,34944)  asum (B*K fp32)
//   [35072,+32MB)  partials: 512 blocks x (32 k x 512 c) fp32

// ---------------- K0: prep ----------------
__global__ __launch_bounds__(256) void prep_kernel(
    const float* __restrict__ cw, unsigned short* __restrict__ cwP,
    float* __restrict__ c2, float* __restrict__ asum) {
  int gid = blockIdx.x * 256 + threadIdx.x;  // 16384 threads = K*C
  if (gid < BB * KK) asum[gid] = 0.f;
  // permuted bf16 codewords (dest-indexed)
  {
    int k = gid >> 9;
    int cc = gid & 511;
    int cs = cc & ~31;
    int w5 = cc & 31;
    int q = w5 >> 3, j = w5 & 7;
    int src_c = cs + 2 * q + (j & 1) + ((j >> 1) << 3);
    cwP[gid] = f2bf(cw[k * CC + src_c]);
  }
  // c2 exact fp32
  __shared__ float c2p[KK][8];
  if (blockIdx.x == 0) {
    int k = threadIdx.x >> 3, j = threadIdx.x & 7;
    const float* row = cw + k * CC + j * 64;
    float s = 0.f;
    for (int i = 0; i < 64; ++i) s = fmaf(row[i], row[i], s);
    c2p[k][j] = s;
    __syncthreads();
    if (threadIdx.x < KK) {
      float t = 0.f;
      for (int j2 = 0; j2 < 8; ++j2) t += c2p[threadIdx.x][j2];
      c2[threadIdx.x] = t;
    }
  }
}

// ---------------- K1: fused logits->softmax->aggregate ----------------
// grid 512 = 16 b x 32 chunks(128 n); block 256 = 4 waves; 2 sub-tiles of 64 n.
// Phase-1 A-frag gather uses the conflict-free c-permutation (matches cwP).
// Epilogue: streaming per-block partial tile (no atomics except tiny asum).
#define XP 72
__global__ __launch_bounds__(256, 2) void fused_kernel(
    const float* __restrict__ x, const unsigned short* __restrict__ cwP,
    const float* __restrict__ c2g, const float* __restrict__ scale,
    float* __restrict__ partials, float* __restrict__ asum) {
  const int b = blockIdx.x >> 5;
  const int chunk = blockIdx.x & 31;
  const int t = threadIdx.x;
  const int w = t >> 6;
  const int l = t & 63;
  const int l15 = l & 15;
  const int q = l >> 4;

  __shared__ char smem[512 * XP * 2 + 32 * XP * 2 + 256];  // 78592 B
  unsigned short* Xl = (unsigned short*)smem;                   // [512][72] u16
  unsigned short* As = (unsigned short*)(smem + 512 * XP * 2);  // [32][72] u16
  float* Sx2p = (float*)(smem + 512 * XP * 2);                  // alias As: [16][68]
  float* Sx2 = (float*)(smem + 512 * XP * 2 + 32 * XP * 2);     // [64]

  const float* xb0 = x + (size_t)b * CC * NN + chunk * 128;

  const float sc0 = scale[l15], sc1 = scale[16 + l15];
  const float cc0 = c2g[l15], cc1 = c2g[16 + l15];

  float4v acc[8][2];
#pragma unroll
  for (int ct = 0; ct < 8; ++ct)
#pragma unroll
    for (int m = 0; m < 2; ++m) acc[ct][m] = (float4v){0.f, 0.f, 0.f, 0.f};
  float s0acc = 0.f, s1acc = 0.f;

  const int f4 = t & 15;   // staging: n = 4*f4 .. 4*f4+3
  const int cr = t >> 4;   // staging: c = cr + 16*i

  for (int sub = 0; sub < 2; ++sub) {
    const float* xb = xb0 + sub * 64;

    // ---- stage x -> Xl bf16, accumulate fp32 x2 partials
    {
      float4v x2p = {0.f, 0.f, 0.f, 0.f};
#pragma unroll 8
      for (int i = 0; i < 32; ++i) {
        const int c = cr + 16 * i;
        float4v v = *(const float4v*)(xb + (size_t)c * NN + 4 * f4);
        x2p.x = fmaf(v.x, v.x, x2p.x);
        x2p.y = fmaf(v.y, v.y, x2p.y);
        x2p.z = fmaf(v.z, v.z, x2p.z);
        x2p.w = fmaf(v.w, v.w, x2p.w);
        unsigned p0 = (unsigned)f2bf(v.x) | ((unsigned)f2bf(v.y) << 16);
        unsigned p1 = (unsigned)f2bf(v.z) | ((unsigned)f2bf(v.w) << 16);
        *(uint2*)&Xl[c * XP + 4 * f4] = make_uint2(p0, p1);
      }
      *(float4v*)&Sx2p[cr * 68 + 4 * f4] = x2p;
    }
    __syncthreads();
    if (t < 64) {
      float s = 0.f;
#pragma unroll
      for (int r = 0; r < 16; ++r) s += Sx2p[r * 68 + t];
      Sx2[t] = s;
    }
    __syncthreads();

    // ---- phase 1: xc via MFMA with permuted c-gather (conflict-free).
    // lane reads rows cs + 2q + {0,1} + {0,8,16,24}: q-groups 2 rows apart
    // = 72 dwords == 8 mod 32 -> banks {0,8,16,24}+l15/2: full partition.
    float4v p0 = {0.f, 0.f, 0.f, 0.f};
    float4v p1 = {0.f, 0.f, 0.f, 0.f};
    const int nrow = w * 16 + l15;
    for (int cs = 0; cs < 512; cs += 32) {
      const int cb2 = cs + 2 * q;
      short8 af;
#pragma unroll
      for (int j = 0; j < 8; ++j) {
        const int c = cb2 + (j & 1) + ((j >> 1) << 3);
        af[j] = (short)Xl[c * XP + nrow];
      }
      short8 b0 = *(const short8*)(cwP + (size_t)l15 * CC + cs + q * 8);
      short8 b1 = *(const short8*)(cwP + (size_t)(16 + l15) * CC + cs + q * 8);
      p0 = __builtin_amdgcn_mfma_f32_16x16x32_bf16(af, b0, p0, 0, 0, 0);
      p1 = __builtin_amdgcn_mfma_f32_16x16x32_bf16(af, b1, p1, 0, 0, 0);
    }

    // ---- softmax per n (lane row r): k spread over l15 lanes
    float a0[4], a1[4];
#pragma unroll
    for (int r = 0; r < 4; ++r) {
      const float xx = Sx2[w * 16 + 4 * q + r];
      float l0 = sc0 * (xx - 2.f * p0[r] + cc0);
      float l1 = sc1 * (xx - 2.f * p1[r] + cc1);
      float m = fmaxf(l0, l1);
      m = fmaxf(m, __shfl_xor(m, 1));
      m = fmaxf(m, __shfl_xor(m, 2));
      m = fmaxf(m, __shfl_xor(m, 4));
      m = fmaxf(m, __shfl_xor(m, 8));
      float e0 = __expf(l0 - m), e1 = __expf(l1 - m);
      float s = e0 + e1;
      s += __shfl_xor(s, 1);
      s += __shfl_xor(s, 2);
      s += __shfl_xor(s, 4);
      s += __shfl_xor(s, 8);
      float inv = 1.0f / s;
      a0[r] = e0 * inv;
      a1[r] = e1 * inv;
    }
    s0acc += a0[0] + a0[1] + a0[2] + a0[3];
    s1acc += a1[0] + a1[1] + a1[2] + a1[3];

    // ---- A-weights -> As[k][n] (alias Sx2p: all reads done at barrier 2)
    {
      unsigned p00 = (unsigned)f2bf(a0[0]) | ((unsigned)f2bf(a0[1]) << 16);
      unsigned p01 = (unsigned)f2bf(a0[2]) | ((unsigned)f2bf(a0[3]) << 16);
      unsigned p10 = (unsigned)f2bf(a1[0]) | ((unsigned)f2bf(a1[1]) << 16);
      unsigned p11 = (unsigned)f2bf(a1[2]) | ((unsigned)f2bf(a1[3]) << 16);
      const int nc = w * 16 + 4 * q;
      *(uint2*)&As[l15 * XP + nc] = make_uint2(p00, p01);
      *(uint2*)&As[(16 + l15) * XP + nc] = make_uint2(p10, p11);
    }
    __syncthreads();

    // ---- phase 2: out_tile[k][c] += A . x^T  (contraction over 64 n)
#pragma unroll
    for (int s = 0; s < 2; ++s) {
      const int nb = s * 32 + q * 8;
      short8 am0 = *(const short8*)&As[l15 * XP + nb];
      short8 am1 = *(const short8*)&As[(16 + l15) * XP + nb];
#pragma unroll
      for (int ct = 0; ct < 8; ++ct) {
        const int c = w * 128 + ct * 16 + l15;
        short8 bx = *(const short8*)&Xl[c * XP + nb];
        acc[ct][0] = __builtin_amdgcn_mfma_f32_16x16x32_bf16(am0, bx, acc[ct][0], 0, 0, 0);
        acc[ct][1] = __builtin_amdgcn_mfma_f32_16x16x32_bf16(am1, bx, acc[ct][1], 0, 0, 0);
      }
    }
    __syncthreads();  // protect Xl/As before next sub's staging
  }

  // ---- epilogue: streaming partial tile [32 k][512 c] for this block
  float* pout = partials + (size_t)blockIdx.x * KK * CC;
#pragma unroll
  for (int ct = 0; ct < 8; ++ct) {
    const int c = w * 128 + ct * 16 + l15;
#pragma unroll
    for (int m = 0; m < 2; ++m)
#pragma unroll
      for (int r = 0; r < 4; ++r) {
        int k = 16 * m + 4 * q + r;
        pout[k * CC + c] = acc[ct][m][r];
      }
  }
  // asum: reduce over q lanes; l15 lanes hold distinct k
  s0acc += __shfl_xor(s0acc, 16);
  s0acc += __shfl_xor(s0acc, 32);
  s1acc += __shfl_xor(s1acc, 16);
  s1acc += __shfl_xor(s1acc, 32);
  if (q == 0) {
    atomicAdd(&asum[b * KK + l15], s0acc);
    atomicAdd(&asum[b * KK + 16 + l15], s1acc);
  }
}

// ---------------- K2: out = sum_chunk partials - asum * cw ----------------
__global__ __launch_bounds__(256) void reduce_kernel(
    const float* __restrict__ partials, const float* __restrict__ asum,
    const float* __restrict__ cw, float* __restrict__ out) {
  int idx = blockIdx.x * 256 + threadIdx.x;  // float4 index, 65536 total
  int b = idx >> 12;
  int k = (idx >> 7) & 31;
  int c4 = idx & 127;

  float4v o = {0.f, 0.f, 0.f, 0.f};
  const float4v* pb = (const float4v*)partials + ((size_t)(b * 32) * KK + k) * 128 + c4;
#pragma unroll 8
  for (int p = 0; p < 32; ++p) {
    float4v v = pb[(size_t)p * KK * 128];
    o.x += v.x;
    o.y += v.y;
    o.z += v.z;
    o.w += v.w;
  }
  float4v wv = ((const float4v*)cw)[k * 128 + c4];
  float a = asum[b * KK + k];
  o.x -= a * wv.x;
  o.y -= a * wv.y;
  o.z -= a * wv.z;
  o.w -= a * wv.w;
  ((float4v*)out)[idx] = o;
}

extern "C" void kernel_launch(void* const* d_in, const int* in_sizes, int n_in,
                              void* d_out, int out_size, void* d_ws, size_t ws_size,
                              hipStream_t stream) {
  const float* x = (const float*)d_in[0];      // (16,512,64,64)
  const float* cw = (const float*)d_in[1];     // (32,512)
  const float* scale = (const float*)d_in[2];  // (32,)
  float* out = (float*)d_out;                  // (16,32,512)
  char* ws = (char*)d_ws;

  float* c2 = (float*)ws;                             // 128 B
  unsigned short* cwP = (unsigned short*)(ws + 128);  // 32 KB
  float* asum = (float*)(ws + 32896);                 // 2 KB
  float* partials = (float*)(ws + 35072);             // 32 MB

  prep_kernel<<<64, 256, 0, stream>>>(cw, cwP, c2, asum);
  fused_kernel<<<512, 256, 0, stream>>>(x, cwP, c2, scale, partials, asum);
  reduce_kernel<<<256, 256, 0, stream>>>(partials, asum, cw, out);
}